// Round 4
// baseline (1642.570 us; speedup 1.0000x reference)
//
#include <hip/hip_runtime.h>
#include <hip/hip_bf16.h>

// SpikingLayer: T=64 sequential LIF steps, cur = W @ f, W ~12% dense.
// Round-4 structure:
//   1. build_csr: single coalesced pass over W -> CSR (f32 val + u16 col),
//      rows padded to 4 entries (zero pads), segments claimed via atomicAdd
//      (layout order nondeterministic, per-row content/order fixed -> output
//      deterministic).
//   2. persist_steps: ONE persistent kernel, 256 blocks x 1024 threads
//      (1 block/CU, all co-resident), hand-rolled device-scope grid barrier.
//      v lives in registers; only the 8192-bit firing mask (256 u32) is
//      exchanged through global memory each step.
// Output layout (flat): fires[T][N] at 0, vs[T][N] at T*N.

#define N_NEURONS 8192
#define T_STEPS   64
#define DECAY     0.9f
#define THRESH    1.0f
#define NNZ_CAP   9437184u  // 14.06% density cap; actual ~12.3% + <=3/row pad
#define STAGE_CAP 1536      // max nnz/row ~1175 (mean 1030) + pad
#define PB_NBLOCKS 256
#define PB_ROWS    32       // N / PB_NBLOCKS
#define PB_THREADS 1024     // 16 waves -> 2 rows/wave

// ws byte layout:
#define WS_V_OFF    0         // 8192 f32  (dense fallback)
#define WS_FB0_OFF  32768     // 8192 f32  (dense fallback)
#define WS_FB1_OFF  65536     // 8192 f32  (dense fallback)
#define WS_M0_OFF   98304     // 1024 B bitmask
#define WS_M1_OFF   99328     // 1024 B bitmask
#define WS_RS_OFF   100352    // 8192 u32 row_start
#define WS_RE_OFF   133120    // 8192 u32 row_end
#define WS_CNT_OFF  165888    // u32 nnz counter
#define WS_BARC_OFF 166016    // u32 barrier arrive count
#define WS_BARG_OFF 166144    // u32 barrier generation
#define WS_VAL_OFF  166272    // NNZ_CAP f32 (16B aligned)
#define WS_COL_OFF  (WS_VAL_OFF + (size_t)NNZ_CAP * 4)
#define WS_REQUIRED (WS_COL_OFF + (size_t)NNZ_CAP * 2)

__global__ __launch_bounds__(256) void init_state(const float* __restrict__ f0,
                                                  const float* __restrict__ v0,
                                                  float* __restrict__ v,
                                                  float* __restrict__ fbuf0,
                                                  unsigned char* __restrict__ m0,
                                                  unsigned* __restrict__ counter,
                                                  unsigned* __restrict__ barc,
                                                  unsigned* __restrict__ barg) {
    int i = blockIdx.x * 256 + threadIdx.x;
    if (i < N_NEURONS) {
        v[i] = v0[i];
        fbuf0[i] = f0[i];
    }
    if (i < N_NEURONS / 8) {
        unsigned b = 0;
        #pragma unroll
        for (int j = 0; j < 8; ++j) b |= (f0[i * 8 + j] != 0.f ? 1u : 0u) << j;
        m0[i] = (unsigned char)b;
    }
    if (i == 0) { *counter = 0u; *barc = 0u; *barg = 0u; }
}

// Single-pass CSR build: coalesced float4 read, ballot-compaction into LDS
// (column order preserved), atomicAdd to claim the (4-padded) segment, then
// coalesced dump. One 256 MB read of W total.
__global__ __launch_bounds__(256) void build_csr(const float* __restrict__ W,
                                                 unsigned* __restrict__ row_start,
                                                 unsigned* __restrict__ row_end,
                                                 float* __restrict__ val,
                                                 unsigned short* __restrict__ col,
                                                 unsigned* __restrict__ counter) {
    __shared__ float          sval[4][STAGE_CAP];
    __shared__ unsigned short scol[4][STAGE_CAP];

    const int wave = threadIdx.x >> 6, lane = threadIdx.x & 63;
    const int row = blockIdx.x * 4 + wave;
    const float4* Wr = (const float4*)(W + (size_t)row * N_NEURONS);
    const unsigned long long lt = ((unsigned long long)1 << lane) - 1;

    unsigned cnt = 0;  // wave-uniform running nnz
    for (int k = 0; k < 32; ++k) {
        const int idx = k * 64 + lane;
        float4 w = Wr[idx];
        const int c0 = idx * 4;
        unsigned long long m;
        m = __ballot(w.x != 0.f);
        if (w.x != 0.f) { unsigned p = cnt + (unsigned)__popcll(m & lt); sval[wave][p] = w.x; scol[wave][p] = (unsigned short)c0; }
        cnt += (unsigned)__popcll(m);
        m = __ballot(w.y != 0.f);
        if (w.y != 0.f) { unsigned p = cnt + (unsigned)__popcll(m & lt); sval[wave][p] = w.y; scol[wave][p] = (unsigned short)(c0 + 1); }
        cnt += (unsigned)__popcll(m);
        m = __ballot(w.z != 0.f);
        if (w.z != 0.f) { unsigned p = cnt + (unsigned)__popcll(m & lt); sval[wave][p] = w.z; scol[wave][p] = (unsigned short)(c0 + 2); }
        cnt += (unsigned)__popcll(m);
        m = __ballot(w.w != 0.f);
        if (w.w != 0.f) { unsigned p = cnt + (unsigned)__popcll(m & lt); sval[wave][p] = w.w; scol[wave][p] = (unsigned short)(c0 + 3); }
        cnt += (unsigned)__popcll(m);
    }

    const unsigned padded = (cnt + 3u) & ~3u;  // float4/uint2 alignment in step
    if (lane < (int)(padded - cnt)) { sval[wave][cnt + lane] = 0.f; scol[wave][cnt + lane] = 0; }

    unsigned gbase = 0;
    if (lane == 0) gbase = atomicAdd(counter, padded);
    gbase = (unsigned)__shfl((int)gbase, 0);
    if (lane == 0) { row_start[row] = gbase; row_end[row] = gbase + padded; }
    __syncthreads();

    for (unsigned i = lane; i < padded; i += 64) {
        val[gbase + i] = sval[wave][i];
        col[gbase + i] = scol[wave][i];
    }
}

__device__ inline void grid_barrier(unsigned* cnt, unsigned* gen) {
    __syncthreads();
    if (threadIdx.x == 0) {
        unsigned g = __hip_atomic_load(gen, __ATOMIC_RELAXED, __HIP_MEMORY_SCOPE_AGENT);
        __threadfence();
        unsigned a = __hip_atomic_fetch_add(cnt, 1u, __ATOMIC_ACQ_REL, __HIP_MEMORY_SCOPE_AGENT);
        if (a == PB_NBLOCKS - 1) {
            __hip_atomic_store(cnt, 0u, __ATOMIC_RELAXED, __HIP_MEMORY_SCOPE_AGENT);
            __hip_atomic_fetch_add(gen, 1u, __ATOMIC_ACQ_REL, __HIP_MEMORY_SCOPE_AGENT);
        } else {
            while (__hip_atomic_load(gen, __ATOMIC_ACQUIRE, __HIP_MEMORY_SCOPE_AGENT) == g)
                __builtin_amdgcn_s_sleep(1);
        }
    }
    __syncthreads();
}

// Persistent: all 64 steps in one kernel. Block b owns rows [32b, 32b+32);
// wave w owns rows 32b+2w, 32b+2w+1 with v in registers.
__global__ __launch_bounds__(PB_THREADS) void persist_steps(
        const unsigned* __restrict__ row_start, const unsigned* __restrict__ row_end,
        const float* __restrict__ val, const unsigned short* __restrict__ col,
        unsigned* __restrict__ mask0, unsigned* __restrict__ mask1,
        const float* __restrict__ v0, float* __restrict__ out,
        unsigned* __restrict__ barc, unsigned* __restrict__ barg) {
    __shared__ unsigned bits[N_NEURONS / 32];  // 1 KB
    __shared__ float sfire[PB_ROWS], sv[PB_ROWS];

    const int tid = threadIdx.x, wave = tid >> 6, lane = tid & 63;
    const int bb = blockIdx.x * PB_ROWS;
    const int r0 = bb + wave * 2, r1 = r0 + 1;
    const unsigned s0 = row_start[r0], e0 = row_end[r0];
    const unsigned s1 = row_start[r1], e1 = row_end[r1];
    float vr0 = v0[r0], vr1 = v0[r1];

    for (int t = 0; t < T_STEPS; ++t) {
        const unsigned* mc = (t & 1) ? mask1 : mask0;
        unsigned* mn       = (t & 1) ? mask0 : mask1;

        if (tid < N_NEURONS / 32) bits[tid] = mc[tid];
        __syncthreads();

        float acc0 = 0.f, acc1 = 0.f;
        for (unsigned k = s0 + (unsigned)lane * 4u; k < e0; k += 256u) {
            float4 w = *(const float4*)(val + k);
            uint2 cc = *(const uint2*)(col + k);
            unsigned c0 = cc.x & 0xffffu, c1 = cc.x >> 16;
            unsigned c2 = cc.y & 0xffffu, c3 = cc.y >> 16;
            if ((bits[c0 >> 5] >> (c0 & 31)) & 1u) acc0 += w.x;
            if ((bits[c1 >> 5] >> (c1 & 31)) & 1u) acc0 += w.y;
            if ((bits[c2 >> 5] >> (c2 & 31)) & 1u) acc0 += w.z;
            if ((bits[c3 >> 5] >> (c3 & 31)) & 1u) acc0 += w.w;
        }
        for (unsigned k = s1 + (unsigned)lane * 4u; k < e1; k += 256u) {
            float4 w = *(const float4*)(val + k);
            uint2 cc = *(const uint2*)(col + k);
            unsigned c0 = cc.x & 0xffffu, c1 = cc.x >> 16;
            unsigned c2 = cc.y & 0xffffu, c3 = cc.y >> 16;
            if ((bits[c0 >> 5] >> (c0 & 31)) & 1u) acc1 += w.x;
            if ((bits[c1 >> 5] >> (c1 & 31)) & 1u) acc1 += w.y;
            if ((bits[c2 >> 5] >> (c2 & 31)) & 1u) acc1 += w.z;
            if ((bits[c3 >> 5] >> (c3 & 31)) & 1u) acc1 += w.w;
        }
        #pragma unroll
        for (int off = 1; off < 64; off <<= 1) {
            acc0 += __shfl_xor(acc0, off);
            acc1 += __shfl_xor(acc1, off);
        }

        vr0 = DECAY * vr0 + acc0;
        vr1 = DECAY * vr1 + acc1;
        float f0 = (vr0 >= THRESH) ? 1.0f : 0.0f;
        float f1 = (vr1 >= THRESH) ? 1.0f : 0.0f;
        if (lane == 0) {
            sfire[wave * 2]     = f0;  sv[wave * 2]     = vr0;
            sfire[wave * 2 + 1] = f1;  sv[wave * 2 + 1] = vr1;
        }
        vr0 = (f0 > 0.f) ? 0.f : vr0;
        vr1 = (f1 > 0.f) ? 0.f : vr1;
        __syncthreads();

        if (tid < PB_ROWS)
            out[(size_t)t * N_NEURONS + bb + tid] = sfire[tid];
        else if (tid < 2 * PB_ROWS)
            out[(size_t)(T_STEPS + t) * N_NEURONS + bb + (tid - PB_ROWS)] = sv[tid - PB_ROWS];
        if (tid == 0) {
            unsigned wd = 0;
            #pragma unroll
            for (int i = 0; i < 32; ++i) wd |= (sfire[i] > 0.f ? 1u : 0u) << i;
            mn[blockIdx.x] = wd;  // release-ordered by barrier arrive
        }
        if (t != T_STEPS - 1) grid_barrier(barc, barg);
    }
}

// ---- Dense fallback if ws is too small for CSR ----
__global__ __launch_bounds__(256) void step_dense(const float* __restrict__ W,
                                                  const float* __restrict__ fin,
                                                  float* __restrict__ fout,
                                                  float* __restrict__ v,
                                                  float* __restrict__ out_fire,
                                                  float* __restrict__ out_v) {
    __shared__ float fs[N_NEURONS];
    const float4* f4 = (const float4*)fin;
    float4* fs4 = (float4*)fs;
    #pragma unroll
    for (int k = 0; k < N_NEURONS / 4 / 256; ++k)
        fs4[k * 256 + threadIdx.x] = f4[k * 256 + threadIdx.x];
    __syncthreads();

    const int wave = threadIdx.x >> 6, lane = threadIdx.x & 63;
    const int row = blockIdx.x * 4 + wave;
    const float4* Wrow = (const float4*)(W + (size_t)row * N_NEURONS);

    float acc = 0.f;
    #pragma unroll 8
    for (int k = 0; k < N_NEURONS / 4 / 64; ++k) {
        const int idx = k * 64 + lane;
        float4 w = Wrow[idx];
        float4 f = fs4[idx];
        acc += w.x * f.x + w.y * f.y + w.z * f.z + w.w * f.w;
    }
    #pragma unroll
    for (int off = 32; off; off >>= 1) acc += __shfl_down(acc, off);

    if (lane == 0) {
        float vn   = DECAY * v[row] + acc;
        float fire = (vn >= THRESH) ? 1.0f : 0.0f;
        out_fire[row] = fire;
        out_v[row]    = vn;
        fout[row]     = fire;
        v[row]        = (fire > 0.f) ? 0.f : vn;
    }
}

extern "C" void kernel_launch(void* const* d_in, const int* in_sizes, int n_in,
                              void* d_out, int out_size, void* d_ws, size_t ws_size,
                              hipStream_t stream) {
    // inputs: x [T,N] (unused), W [N,N], f0 [N], v0 [N]
    const float* W  = (const float*)d_in[1];
    const float* f0 = (const float*)d_in[2];
    const float* v0 = (const float*)d_in[3];
    float* out = (float*)d_out;

    char* ws = (char*)d_ws;
    float* v   = (float*)(ws + WS_V_OFF);
    float* fb0 = (float*)(ws + WS_FB0_OFF);
    float* fb1 = (float*)(ws + WS_FB1_OFF);
    unsigned char* m0 = (unsigned char*)(ws + WS_M0_OFF);
    unsigned* mask0 = (unsigned*)(ws + WS_M0_OFF);
    unsigned* mask1 = (unsigned*)(ws + WS_M1_OFF);
    unsigned* row_start = (unsigned*)(ws + WS_RS_OFF);
    unsigned* row_end   = (unsigned*)(ws + WS_RE_OFF);
    unsigned* counter   = (unsigned*)(ws + WS_CNT_OFF);
    unsigned* barc      = (unsigned*)(ws + WS_BARC_OFF);
    unsigned* barg      = (unsigned*)(ws + WS_BARG_OFF);
    float* val          = (float*)(ws + WS_VAL_OFF);
    unsigned short* col = (unsigned short*)(ws + WS_COL_OFF);

    init_state<<<(N_NEURONS + 255) / 256, 256, 0, stream>>>(
        f0, v0, v, fb0, m0, counter, barc, barg);

    if (ws_size >= WS_REQUIRED) {
        build_csr<<<N_NEURONS / 4, 256, 0, stream>>>(W, row_start, row_end, val, col, counter);
        persist_steps<<<PB_NBLOCKS, PB_THREADS, 0, stream>>>(
            row_start, row_end, val, col, mask0, mask1, v0, out, barc, barg);
    } else {
        float* fbufs[2] = {fb0, fb1};
        for (int t = 0; t < T_STEPS; ++t) {
            const float* fin = fbufs[t & 1];
            float* fout      = fbufs[(t + 1) & 1];
            step_dense<<<N_NEURONS / 4, 256, 0, stream>>>(
                W, fin, fout, v,
                out + (size_t)t * N_NEURONS,
                out + (size_t)(T_STEPS + t) * N_NEURONS);
        }
    }
}